// Round 2
// baseline (405.555 us; speedup 1.0000x reference)
//
#include <hip/hip_runtime.h>
#include <cstdint>

#define BATCH 8
#define SEQ   4096
#define DIN   1024
#define DST   64
#define CHUNK 64
#define NC    (SEQ/CHUNK)   // 64 chunks per batch
#define NBLK  (BATCH*NC)    // 512 (b,c) blocks

typedef __attribute__((ext_vector_type(8))) short short8;
typedef __attribute__((ext_vector_type(4))) float f32x4;

__device__ __forceinline__ short f2bf(float f) {
    union { float f; unsigned u; } v; v.f = f;
    unsigned r = v.u + 0x7fffu + ((v.u >> 16) & 1u);   // RNE
    return (short)(r >> 16);
}
__device__ __forceinline__ float softplus_f(float x) {
    return (x > 20.f) ? x : log1pf(expf(x));
}

// ---------------- k0: precompute ----------------
// blocks 0..63: row n of B_bar (bf16) + reduction a[n] = mean_i exp(delta_i * A_n)
// blocks 64..79: convert C (f32 [1024][64]) -> bf16; block 64 also zeroes ctl
__global__ void ssm_k0(const float* __restrict__ logA, const float* __restrict__ Bm,
                       const float* __restrict__ Cm, const float* __restrict__ logdelta,
                       short* __restrict__ Bb, short* __restrict__ Cb,
                       float* __restrict__ a_o, float* __restrict__ l2a_o,
                       float* __restrict__ aL_o, unsigned* __restrict__ ctl)
{
    __shared__ float red[256];
    int blk = blockIdx.x, tid = threadIdx.x;
    if (blk < DST) {
        int n = blk;
        float An = -expf(logA[n]);
        float acc = 0.f;
        #pragma unroll
        for (int ii = 0; ii < DIN/256; ++ii) {
            int i = ii*256 + tid;
            float dlt = softplus_f(logdelta[i]);
            Bb[n*DIN + i] = f2bf(Bm[n*DIN + i] * dlt);
            acc += expf(dlt * An);
        }
        red[tid] = acc; __syncthreads();
        for (int s = 128; s > 0; s >>= 1) {
            if (tid < s) red[tid] += red[tid + s];
            __syncthreads();
        }
        if (tid == 0) {
            float a = red[0] * (1.f/DIN);
            a_o[n]   = a;
            l2a_o[n] = log2f(a);
            float p = a;
            #pragma unroll
            for (int q = 0; q < 6; ++q) p = p*p;      // a^64 = a^CHUNK
            aL_o[n] = p;
        }
    } else {
        if (blk == DST) {                              // zero flags + ticket
            for (int g = tid; g <= NBLK; g += 256) ctl[g] = 0u;
        }
        int base = (blk - DST) * (DIN*DST/16);
        for (int e = tid; e < DIN*DST/16; e += 256)
            Cb[base + e] = f2bf(Cm[base + e]);
    }
}

// ---------------- fused: Bu GEMM -> scan -> lookback -> correct -> y GEMM ----
// one block per (b, chunk). 8 waves of 64. Ticket via atomicAdd guarantees
// predecessor chunks are dispatched before/with us -> lookback cannot deadlock.
__global__ __launch_bounds__(512, 4) void ssm_fused(
    const float* __restrict__ u, const short* __restrict__ Bb,
    const short* __restrict__ Cb, const float* __restrict__ a_i,
    const float* __restrict__ l2a, const float* __restrict__ aLp,
    const float* __restrict__ Dv, unsigned* __restrict__ ctl,
    float* __restrict__ carryG, float* __restrict__ inclG,
    float* __restrict__ y)
{
    __shared__ float bu[2][CHUNK][DST];   // 32 KB: K-split halves; bu[0] becomes xloc
    __shared__ short xs[CHUNK][DST];      // 8 KB: corrected x in bf16
    __shared__ float E_lds[DST];
    __shared__ unsigned vb_sh;

    int tid = threadIdx.x;
    if (tid == 0) vb_sh = atomicAdd(&ctl[NBLK], 1u);
    __syncthreads();
    int vb = (int)vb_sh;
    int b = vb >> 6, c = vb & (NC-1);

    int w = tid >> 6, lane = tid & 63;
    int m = lane & 15, quad = lane >> 4;

    // ---- phase A: Bu = B_bar @ u^T for 64 t-rows (8 waves: 4 m-tiles x 2 K-halves)
    {
        int wr = w & 3, wk = w >> 2;
        long row = ((long)b << 12) + (c << 6) + (wr << 4) + m;
        const float* up  = u  + row * DIN + wk*(DIN/2) + quad*8;
        const short* bb0 = Bb + wk*(DIN/2) + quad*8;
        f32x4 acc0={0,0,0,0}, acc1={0,0,0,0}, acc2={0,0,0,0}, acc3={0,0,0,0};
        #pragma unroll 4
        for (int ks = 0; ks < DIN/64; ++ks) {
            const float4* uv = (const float4*)(up + ks*32);
            float4 ua = uv[0], ub2 = uv[1];
            short8 af;
            af[0]=f2bf(ua.x);  af[1]=f2bf(ua.y);  af[2]=f2bf(ua.z);  af[3]=f2bf(ua.w);
            af[4]=f2bf(ub2.x); af[5]=f2bf(ub2.y); af[6]=f2bf(ub2.z); af[7]=f2bf(ub2.w);
            const short* bbase = bb0 + ks*32;
            short8 b0 = *(const short8*)(bbase + ( 0 + m)*DIN);
            short8 b1 = *(const short8*)(bbase + (16 + m)*DIN);
            short8 b2 = *(const short8*)(bbase + (32 + m)*DIN);
            short8 b3 = *(const short8*)(bbase + (48 + m)*DIN);
            acc0 = __builtin_amdgcn_mfma_f32_16x16x32_bf16(af, b0, acc0, 0,0,0);
            acc1 = __builtin_amdgcn_mfma_f32_16x16x32_bf16(af, b1, acc1, 0,0,0);
            acc2 = __builtin_amdgcn_mfma_f32_16x16x32_bf16(af, b2, acc2, 0,0,0);
            acc3 = __builtin_amdgcn_mfma_f32_16x16x32_bf16(af, b3, acc3, 0,0,0);
        }
        int trow = (wr << 4) + (quad << 2);
        #pragma unroll
        for (int r = 0; r < 4; ++r) {
            bu[wk][trow + r][ 0 + m] = acc0[r];
            bu[wk][trow + r][16 + m] = acc1[r];
            bu[wk][trow + r][32 + m] = acc2[r];
            bu[wk][trow + r][48 + m] = acc3[r];
        }
    }
    __syncthreads();

    // ---- phase B: wave 0 = local scan (into bu[0]) + decoupled lookback
    if (tid < DST) {
        int n = tid;
        float an  = a_i[n];
        float aLn = aLp[n];
        float x = 0.f;
        #pragma unroll 8
        for (int t = 0; t < CHUNK; ++t) {
            x = x * an + (bu[0][t][n] + bu[1][t][n]);
            bu[0][t][n] = x;                     // xloc kept in LDS
        }
        float E = 0.f;
        if (c > 0) {
            // publish aggregate
            __hip_atomic_store(&carryG[vb*DST + n], x, __ATOMIC_RELAXED, __HIP_MEMORY_SCOPE_AGENT);
            if (n == 0)
                __hip_atomic_store(&ctl[vb], 1u, __ATOMIC_RELEASE, __HIP_MEMORY_SCOPE_AGENT);
            // walk predecessors: E = sum_{p<c} carry[p] * aL^(c-1-p), short-circuit on inclusive
            float f = 1.f;
            for (int p = vb - 1; ; --p) {
                unsigned st = 0;
                if (n == 0) {
                    st = __hip_atomic_load(&ctl[p], __ATOMIC_ACQUIRE, __HIP_MEMORY_SCOPE_AGENT);
                    while (st == 0u) {
                        __builtin_amdgcn_s_sleep(2);
                        st = __hip_atomic_load(&ctl[p], __ATOMIC_ACQUIRE, __HIP_MEMORY_SCOPE_AGENT);
                    }
                }
                st = (unsigned)__shfl((int)st, 0);
                if (st == 2u) {
                    E += f * __hip_atomic_load(&inclG[p*DST + n], __ATOMIC_RELAXED, __HIP_MEMORY_SCOPE_AGENT);
                    break;
                }
                E += f * __hip_atomic_load(&carryG[p*DST + n], __ATOMIC_RELAXED, __HIP_MEMORY_SCOPE_AGENT);
                f *= aLn;
            }
        }
        // publish inclusive prefix: state after this chunk = x + aL * E
        __hip_atomic_store(&inclG[vb*DST + n], x + aLn * E, __ATOMIC_RELAXED, __HIP_MEMORY_SCOPE_AGENT);
        if (n == 0)
            __hip_atomic_store(&ctl[vb], 2u, __ATOMIC_RELEASE, __HIP_MEMORY_SCOPE_AGENT);
        E_lds[n] = E;
    }
    __syncthreads();

    // ---- phase C: correct x with entering state, convert to bf16 in LDS
    {
        int t  = tid >> 3;              // 0..63
        int n0 = (tid & 7) * 8;         // 8 n per thread
        float jp = (float)(t + 1);
        float xv[8];
        #pragma unroll
        for (int k2 = 0; k2 < 8; ++k2) {
            int n = n0 + k2;
            xv[k2] = bu[0][t][n] + exp2f(jp * l2a[n]) * E_lds[n];
        }
        short8 xsv;
        #pragma unroll
        for (int k2 = 0; k2 < 8; ++k2) xsv[k2] = f2bf(xv[k2]);
        *(short8*)(&xs[t][n0]) = xsv;
    }
    __syncthreads();

    // ---- phase D: y = C @ x + D*u for the 64 t-rows (8 waves: 4 t-tiles x 2 i-halves)
    {
        int l16 = lane & 15;
        int tt = w & 3, ihalf = w >> 2;
        short8 x0 = *(const short8*)(&xs[tt*16 + l16][ 0 + quad*8]);
        short8 x1 = *(const short8*)(&xs[tt*16 + l16][32 + quad*8]);
        long trow = ((long)b << 12) + (c << 6) + tt*16 + l16;
        const float* urow = u + trow * DIN;
        float* yrow = y + trow * DIN;
        #pragma unroll 4
        for (int ii = 0; ii < 32; ++ii) {
            int i0 = (ihalf*32 + ii) * 16;
            const short* cb = Cb + (long)(i0 + l16)*DST + quad*8;
            short8 c0 = *(const short8*)(cb);
            short8 c1 = *(const short8*)(cb + 32);
            f32x4 acc = {0,0,0,0};
            acc = __builtin_amdgcn_mfma_f32_16x16x32_bf16(c0, x0, acc, 0,0,0);
            acc = __builtin_amdgcn_mfma_f32_16x16x32_bf16(c1, x1, acc, 0,0,0);
            int ib = i0 + (quad << 2);
            float4 dd = *(const float4*)(Dv + ib);
            float4 uu = *(const float4*)(urow + ib);
            float4 o;
            o.x = acc[0] + dd.x*uu.x;
            o.y = acc[1] + dd.y*uu.y;
            o.z = acc[2] + dd.z*uu.z;
            o.w = acc[3] + dd.w*uu.w;
            *(float4*)(yrow + ib) = o;
        }
    }
}

extern "C" void kernel_launch(void* const* d_in, const int* in_sizes, int n_in,
                              void* d_out, int out_size, void* d_ws, size_t ws_size,
                              hipStream_t stream)
{
    const float* u        = (const float*)d_in[0];
    const float* logA     = (const float*)d_in[1];
    const float* Bm       = (const float*)d_in[2];
    const float* Cm       = (const float*)d_in[3];
    const float* D        = (const float*)d_in[4];
    const float* logdelta = (const float*)d_in[5];
    float* y = (float*)d_out;

    char* ws = (char*)d_ws;
    unsigned* ctl   = (unsigned*)(ws);                       // (NBLK+1) u32, 4 KB slot
    float*    carry = (float*)(ws + 4*1024);                 // 128 KB
    float*    incl  = (float*)(ws + 4*1024 + 128*1024);      // 128 KB
    short*    Bb    = (short*)(ws + 4*1024 + 256*1024);      // 128 KB bf16 B_bar
    short*    Cb    = (short*)(ws + 4*1024 + 384*1024);      // 128 KB bf16 C
    float*    a_o   = (float*)(ws + 4*1024 + 512*1024);
    float*    l2a_o = a_o + 64;
    float*    aL_o  = a_o + 128;

    hipLaunchKernelGGL(ssm_k0, dim3(DST + 16), dim3(256), 0, stream,
                       logA, Bm, Cm, logdelta, Bb, Cb, a_o, l2a_o, aL_o, ctl);
    hipLaunchKernelGGL(ssm_fused, dim3(NBLK), dim3(512), 0, stream,
                       u, Bb, Cb, a_o, l2a_o, aL_o, D, ctl, carry, incl, y);
}

// Round 3
// 318.174 us; speedup vs baseline: 1.2746x; 1.2746x over previous
//
#include <hip/hip_runtime.h>
#include <cstdint>

#define BATCH 8
#define SEQ   4096
#define DIN   1024
#define DST   64
#define CHUNK 32
#define NCC   (SEQ/CHUNK)    // 128 chunks per batch
#define NBLK1 (BATCH*NCC)    // 1024 k1 blocks

typedef __attribute__((ext_vector_type(8))) short short8;
typedef __attribute__((ext_vector_type(4))) short short4v;
typedef __attribute__((ext_vector_type(4))) float f32x4;

__device__ __forceinline__ short f2bf(float f) {
    union { float f; unsigned u; } v; v.f = f;
    unsigned r = v.u + 0x7fffu + ((v.u >> 16) & 1u);   // RNE
    return (short)(r >> 16);
}
__device__ __forceinline__ float softplus_f(float x) {
    return (x > 20.f) ? x : log1pf(expf(x));
}

// ---------------- k0: precompute ----------------
// blocks 0..63: row n of B_bar (bf16) + reduction a[n] = mean_i exp(delta_i * A_n)
// blocks 64..79: convert C (f32 [1024][64]) -> bf16 same layout
__global__ void ssm_k0(const float* __restrict__ logA, const float* __restrict__ Bm,
                       const float* __restrict__ Cm, const float* __restrict__ logdelta,
                       short* __restrict__ Bb, short* __restrict__ Cb,
                       float* __restrict__ a_o, float* __restrict__ l2a_o,
                       float* __restrict__ aL_o)
{
    __shared__ float red[256];
    int blk = blockIdx.x, tid = threadIdx.x;
    if (blk < DST) {
        int n = blk;
        float An = -expf(logA[n]);
        float acc = 0.f;
        #pragma unroll
        for (int ii = 0; ii < DIN/256; ++ii) {
            int i = ii*256 + tid;
            float dlt = softplus_f(logdelta[i]);
            Bb[n*DIN + i] = f2bf(Bm[n*DIN + i] * dlt);
            acc += expf(dlt * An);
        }
        red[tid] = acc; __syncthreads();
        for (int s = 128; s > 0; s >>= 1) {
            if (tid < s) red[tid] += red[tid + s];
            __syncthreads();
        }
        if (tid == 0) {
            float a = red[0] * (1.f/DIN);
            a_o[n]   = a;
            l2a_o[n] = log2f(a);
            float p = a;
            #pragma unroll
            for (int q = 0; q < 5; ++q) p = p*p;      // a^32 = a^CHUNK
            aL_o[n] = p;
        }
    } else {
        int base = (blk - DST) * (DIN*DST/16);
        for (int e = tid; e < DIN*DST/16; e += 256)
            Cb[base + e] = f2bf(Cm[base + e]);
    }
}

// ---------------- k1: Bu GEMM (MFMA) + chunk-local scan ----------------
// block = one (batch, 32-t chunk). 4 waves: wr = m-tile (2), wk = K-half (2).
// 1024 blocks -> 4 blocks/CU, 16 waves/CU (vs 2 blocks/CU at CHUNK=64).
__global__ __launch_bounds__(256) void ssm_k1(
    const float* __restrict__ u, const short* __restrict__ Bb,
    const float* __restrict__ a_i, float* __restrict__ xloc, float* __restrict__ carry)
{
    int blk = blockIdx.x;                 // b*NCC + cc
    int b = blk >> 7, cc = blk & (NCC-1);
    int tid = threadIdx.x;
    int w = tid >> 6, lane = tid & 63;
    int wr = w & 1, wk = w >> 1;
    int m = lane & 15, quad = lane >> 4;

    long row = ((long)b << 12) + (cc << 5) + (wr << 4) + m;   // global bt row
    const float* up  = u  + row * DIN + wk*(DIN/2) + quad * 8;
    const short* bb0 = Bb + wk*(DIN/2) + quad * 8;

    f32x4 acc0 = {0,0,0,0}, acc1 = {0,0,0,0}, acc2 = {0,0,0,0}, acc3 = {0,0,0,0};

    #pragma unroll 4
    for (int ks = 0; ks < DIN/64; ++ks) {     // 16 iters of K=32 within this half
        const float4* uv = (const float4*)(up + ks*32);
        float4 ua = uv[0];
        float4 ub = uv[1];
        short8 af;
        af[0]=f2bf(ua.x); af[1]=f2bf(ua.y); af[2]=f2bf(ua.z); af[3]=f2bf(ua.w);
        af[4]=f2bf(ub.x); af[5]=f2bf(ub.y); af[6]=f2bf(ub.z); af[7]=f2bf(ub.w);
        const short* bbase = bb0 + ks*32;
        short8 b0 = *(const short8*)(bbase + ( 0 + m)*DIN);
        short8 b1 = *(const short8*)(bbase + (16 + m)*DIN);
        short8 b2 = *(const short8*)(bbase + (32 + m)*DIN);
        short8 b3 = *(const short8*)(bbase + (48 + m)*DIN);
        acc0 = __builtin_amdgcn_mfma_f32_16x16x32_bf16(af, b0, acc0, 0,0,0);
        acc1 = __builtin_amdgcn_mfma_f32_16x16x32_bf16(af, b1, acc1, 0,0,0);
        acc2 = __builtin_amdgcn_mfma_f32_16x16x32_bf16(af, b2, acc2, 0,0,0);
        acc3 = __builtin_amdgcn_mfma_f32_16x16x32_bf16(af, b3, acc3, 0,0,0);
    }

    __shared__ float bu[2][CHUNK][DST+1];     // +1 pad: MFMA-store 4-way conflict -> none
    int trow = (wr << 4) + (quad << 2);
    #pragma unroll
    for (int r = 0; r < 4; ++r) {
        bu[wk][trow + r][ 0 + m] = acc0[r];
        bu[wk][trow + r][16 + m] = acc1[r];
        bu[wk][trow + r][32 + m] = acc2[r];
        bu[wk][trow + r][48 + m] = acc3[r];
    }
    __syncthreads();

    if (tid < DST) {                       // wave 0: 32-step local scan
        int n = tid;
        float an = a_i[n];
        float x = 0.f;
        float* xp = xloc + (((long)b << 12) + (cc << 5)) * DST + n;
        #pragma unroll
        for (int t = 0; t < CHUNK; ++t) {
            x = x * an + (bu[0][t][n] + bu[1][t][n]);
            xp[(long)t * DST] = x;
        }
        carry[blk * DST + n] = x;
    }
}

// ---------------- k3: inline prefix + correction + y GEMM ----------------
// block = 16 t-rows x full I=1024. E (entering state) computed in-block by a
// Horner walk over predecessor carries (L2-resident) — no k2 kernel, no waiting.
__global__ __launch_bounds__(256) void ssm_k3(
    const float* __restrict__ u, const float* __restrict__ xloc,
    const float* __restrict__ carry, const float* __restrict__ aLp,
    const float* __restrict__ l2a, const short* __restrict__ Cb,
    const float* __restrict__ Dv, float* __restrict__ y)
{
    int tblk = blockIdx.x;                 // 2048 blocks
    long t0 = (long)tblk << 4;
    int b = (int)(t0 >> 12);
    int tloc0 = (int)(t0 & (SEQ-1));
    int c = tloc0 >> 5;                    // 16-row tile never crosses a 32-chunk
    int jbase = tloc0 & (CHUNK-1);

    __shared__ float E_lds[DST];
    __shared__ short xs[16][72];           // +8 pad: frag ds_read 16-way -> 2-way (free)

    int tid = threadIdx.x;
    if (tid < DST) {                       // Horner prefix over carries of chunks < c
        int n = tid;
        float al = aLp[n];
        float E = 0.f;
        const float* cp = carry + (b*NCC)*DST + n;
        #pragma unroll 4
        for (int p = 0; p < c; ++p)
            E = E * al + cp[p*DST];
        E_lds[n] = E;
    }
    __syncthreads();

    {
        int m  = tid >> 4;
        int n0 = (tid & 15) * 4;
        long t = t0 + m;
        int j  = jbase + m;
        float4 xv = *(const float4*)(xloc + t*DST + n0);
        float4 la = *(const float4*)(l2a + n0);
        float4 Ev = *(const float4*)(&E_lds[n0]);
        float jp = (float)(j + 1);
        short4v xsv;
        xsv[0] = f2bf(xv.x + exp2f(jp*la.x)*Ev.x);
        xsv[1] = f2bf(xv.y + exp2f(jp*la.y)*Ev.y);
        xsv[2] = f2bf(xv.z + exp2f(jp*la.z)*Ev.z);
        xsv[3] = f2bf(xv.w + exp2f(jp*la.w)*Ev.w);
        *(short4v*)(&xs[m][n0]) = xsv;
    }
    __syncthreads();

    int w = tid >> 6, lane = tid & 63;
    int l16 = lane & 15, quad = lane >> 4;

    // B-operand: x fragment (col = t = l16, k = quad*8 + j) — hoisted, reused all ii
    short8 x0 = *(const short8*)(&xs[l16][ 0 + quad*8]);
    short8 x1 = *(const short8*)(&xs[l16][32 + quad*8]);

    long trow = t0 + l16;
    const float* urow = u + trow*DIN;
    float* yrow = y + trow*DIN;

    #pragma unroll 4
    for (int ii = 0; ii < 16; ++ii) {
        int i0 = (ii*4 + w) * 16;
        // A-operand: C fragment (row = i = i0+l16, k = quad*8 + j)
        const short* cb = Cb + (long)(i0 + l16)*DST + quad*8;
        short8 c0 = *(const short8*)(cb);
        short8 c1 = *(const short8*)(cb + 32);
        f32x4 acc = {0,0,0,0};
        acc = __builtin_amdgcn_mfma_f32_16x16x32_bf16(c0, x0, acc, 0,0,0);
        acc = __builtin_amdgcn_mfma_f32_16x16x32_bf16(c1, x1, acc, 0,0,0);
        // D[row = quad*4+r][col = l16] -> i = i0 + quad*4 + r, t = t0 + l16
        int ib = i0 + (quad << 2);
        float4 dd = *(const float4*)(Dv + ib);
        float4 uu = *(const float4*)(urow + ib);
        float4 o;
        o.x = acc[0] + dd.x*uu.x;
        o.y = acc[1] + dd.y*uu.y;
        o.z = acc[2] + dd.z*uu.z;
        o.w = acc[3] + dd.w*uu.w;
        *(float4*)(yrow + ib) = o;
    }
}

extern "C" void kernel_launch(void* const* d_in, const int* in_sizes, int n_in,
                              void* d_out, int out_size, void* d_ws, size_t ws_size,
                              hipStream_t stream)
{
    const float* u        = (const float*)d_in[0];
    const float* logA     = (const float*)d_in[1];
    const float* Bm       = (const float*)d_in[2];
    const float* Cm       = (const float*)d_in[3];
    const float* D        = (const float*)d_in[4];
    const float* logdelta = (const float*)d_in[5];
    float* y = (float*)d_out;

    char* ws = (char*)d_ws;
    float* xloc  = (float*)(ws);                             // 8 MiB
    float* carry = (float*)(ws + 8u*1024*1024);              // 256 KiB (1024*64 f32)
    short* Bb    = (short*)(ws + 8u*1024*1024 + 256*1024);   // 128 KiB bf16 B_bar
    short* Cb    = (short*)(ws + 8u*1024*1024 + 384*1024);   // 128 KiB bf16 C
    float* a_o   = (float*)(ws + 8u*1024*1024 + 512*1024);
    float* l2a_o = a_o + 64;
    float* aL_o  = a_o + 128;

    hipLaunchKernelGGL(ssm_k0, dim3(DST + 16), dim3(256), 0, stream,
                       logA, Bm, Cm, logdelta, Bb, Cb, a_o, l2a_o, aL_o);
    hipLaunchKernelGGL(ssm_k1, dim3(NBLK1), dim3(256), 0, stream,
                       u, Bb, a_o, xloc, carry);
    hipLaunchKernelGGL(ssm_k3, dim3((BATCH*SEQ)/16), dim3(256), 0, stream,
                       u, xloc, carry, aL_o, l2a_o, Cb, D, y);
}